// Round 1
// baseline (408.167 us; speedup 1.0000x reference)
//
#include <hip/hip_runtime.h>
#include <stdint.h>
#include <math.h>

// ---------------- problem constants ----------------
constexpr int D_ = 128;                 // quantum_dim
constexpr int Q_ = 16;                  // num_qubits
constexpr int KDIM = 4096;              // S / NQ
constexpr uint32_t SD_ = 65536u * 128u; // S*D = 8,388,608 (per-batch stride in flat [B,S,D])

// ---------------- threefry2x32 (JAX-exact, 20 rounds) ----------------
__host__ __device__ static inline void tfround(uint32_t& x0, uint32_t& x1, int r) {
    x0 += x1;
    x1 = (x1 << r) | (x1 >> (32 - r));
    x1 ^= x0;
}

__host__ __device__ static inline void tf2x32(uint32_t k0, uint32_t k1,
                                              uint32_t x0, uint32_t x1,
                                              uint32_t& o0, uint32_t& o1) {
    uint32_t ks2 = k0 ^ k1 ^ 0x1BD11BDAu;
    x0 += k0; x1 += k1;
    tfround(x0, x1, 13); tfround(x0, x1, 15); tfround(x0, x1, 26); tfround(x0, x1, 6);
    x0 += k1;  x1 += ks2 + 1u;
    tfround(x0, x1, 17); tfround(x0, x1, 29); tfround(x0, x1, 16); tfround(x0, x1, 24);
    x0 += ks2; x1 += k0 + 2u;
    tfround(x0, x1, 13); tfround(x0, x1, 15); tfround(x0, x1, 26); tfround(x0, x1, 6);
    x0 += k0;  x1 += k1 + 3u;
    tfround(x0, x1, 17); tfround(x0, x1, 29); tfround(x0, x1, 16); tfround(x0, x1, 24);
    x0 += k1;  x1 += ks2 + 4u;
    tfround(x0, x1, 13); tfround(x0, x1, 15); tfround(x0, x1, 26); tfround(x0, x1, 6);
    x0 += ks2; x1 += k0 + 5u;
    o0 = x0; o1 = x1;
}

// bits -> [0,1): bitcast((bits>>9)|0x3f800000) - 1   (subtraction is exact)
__device__ __forceinline__ float bits_to_f01(uint32_t r) {
    return __uint_as_float((r >> 9) | 0x3f800000u) - 1.0f;
}

// XLA ErfInv32 (Giles polynomial, w = -log1p(-x*x)) — noise path, ulp-tolerant
__device__ __forceinline__ float erfinv_xla(float x) {
    float w = -log1pf(-x * x);
    float p;
    if (w < 5.0f) {
        w -= 2.5f;
        p = 2.81022636e-08f;
        p = fmaf(p, w, 3.43273939e-07f);
        p = fmaf(p, w, -3.5233877e-06f);
        p = fmaf(p, w, -4.39150654e-06f);
        p = fmaf(p, w, 0.00021858087f);
        p = fmaf(p, w, -0.00125372503f);
        p = fmaf(p, w, -0.00417768164f);
        p = fmaf(p, w, 0.246640727f);
        p = fmaf(p, w, 1.50140941f);
    } else {
        w = sqrtf(w) - 3.0f;
        p = -0.000200214257f;
        p = fmaf(p, w, 0.000100950558f);
        p = fmaf(p, w, 0.00134934322f);
        p = fmaf(p, w, -0.00367342844f);
        p = fmaf(p, w, 0.00573950773f);
        p = fmaf(p, w, -0.0076224613f);
        p = fmaf(p, w, 0.00943887047f);
        p = fmaf(p, w, 1.00167406f);
        p = fmaf(p, w, 2.83297682f);
    }
    return p * x;
}

// ---------------- kernel 1: prep (softmax ew, phase, zero argmax slots) ----------------
__global__ __launch_bounds__(512) void qsl_prep(const float* __restrict__ ang,
                                                const float* __restrict__ ent,
                                                float* __restrict__ ws_f,
                                                unsigned long long* __restrict__ keys) {
    int t = threadIdx.x;
    keys[t] = 0ULL;  // 512 packed (val,idx) argmax slots, one per (b,d)
    if (t < 16) {
        float row[16];
        float m = -INFINITY;
        for (int j = 0; j < 16; j++) { row[j] = ent[t * 16 + j]; m = fmaxf(m, row[j]); }
        float s = 0.f;
        for (int j = 0; j < 16; j++) { row[j] = expf(row[j] - m); s += row[j]; }
        for (int j = 0; j < 16; j++) ws_f[t * 16 + j] = row[j] / s;
    }
    if (t == 0) {
        float a = 0.f;
        for (int i = 0; i < 48; i++) a += ang[i];
        ws_f[256] = cosf(a);
        ws_f[257] = sinf(a);
    }
}

// ---------------- kernel 2: main (mix + RNG + gumbel argmax) ----------------
__global__ __launch_bounds__(256) void qsl_main(const float* __restrict__ qre,
                                                const float* __restrict__ qim,
                                                const float* __restrict__ ws_f,
                                                unsigned long long* __restrict__ keys,
                                                uint32_t kA0, uint32_t kA1,
                                                uint32_t kB0, uint32_t kB1,
                                                uint32_t kC0, uint32_t kC1,
                                                float coh, float nc) {
    __shared__ float ew_s[256];
    __shared__ float red_v[4][128];
    __shared__ uint32_t red_i[4][128];

    const int d = threadIdx.x;               // 0..127
    const int y = threadIdx.y;               // 0..1
    const int kk = blockIdx.x * 2 + y;       // 0..4095 (k index in S = q*4096 + k)

    ew_s[y * 128 + d] = ws_f[y * 128 + d];
    __syncthreads();
    const float pr = ws_f[256], pi = ws_f[257];

    // load the 16 q-rows of this (k,d) column factor — each qw element read once
    float are[16], aim[16];
#pragma unroll
    for (int p = 0; p < 16; p++) {
        int off = (p * KDIM + kk) * D_ + d;
        are[p] = qre[off];
        aim[p] = qim[off];
    }

    float best[4];
    uint32_t bidx[4];
#pragma unroll
    for (int b = 0; b < 4; b++) { best[b] = -INFINITY; bidx[b] = 0u; }

    for (int q = 0; q < 16; q++) {
        // entanglement mix: ENT * sum_p ew[q,p]*A[p] + (1-ENT)*A[q]
        float mr = 0.f, mi = 0.f;
#pragma unroll
        for (int p = 0; p < 16; p++) {
            float w = ew_s[q * 16 + p];
            mr = fmaf(w, are[p], mr);
            mi = fmaf(w, aim[p], mi);
        }
        mr = fmaf(0.8f, mr, 0.2f * are[q]);
        mi = fmaf(0.8f, mi, 0.2f * aim[q]);
        // global phase, then decoherence scale
        float sr = mr * pr - mi * pi;
        float si = mr * pi + mi * pr;
        float br = sr * coh, bi = si * coh;

        uint32_t s = (uint32_t)q * (uint32_t)KDIM + (uint32_t)kk;
        uint32_t base_n = s * (uint32_t)D_ + (uint32_t)d;  // flat [b=0,s,d]

        // partitionable threefry: bits[n] = w0^w1 of enc(key, (0, n))
        uint32_t rn0[4], rn1[4], ru[4];
#pragma unroll
        for (int b = 0; b < 4; b++) {
            uint32_t n = base_n + (uint32_t)b * SD_;
            uint32_t w0, w1;
            tf2x32(kA0, kA1, 0u, n, w0, w1); rn0[b] = w0 ^ w1;
            tf2x32(kB0, kB1, 0u, n, w0, w1); rn1[b] = w0 ^ w1;
            tf2x32(kC0, kC1, 0u, n, w0, w1); ru[b]  = w0 ^ w1;
        }

#pragma unroll
        for (int b = 0; b < 4; b++) {
            // normal(): u in [nextafter(-1,0), 1), sqrt(2)*erfinv(u)
            const float nlo = -0.99999994f;      // nextafterf(-1,0)
            const float ndf = 1.0f - nlo;
            float f0 = bits_to_f01(rn0[b]);
            float x0 = fmaxf(nlo, __fadd_rn(__fmul_rn(f0, ndf), nlo));
            float f1 = bits_to_f01(rn1[b]);
            float x1 = fmaxf(nlo, __fadd_rn(__fmul_rn(f1, ndf), nlo));
            float nr = 1.41421356f * erfinv_xla(x0);
            float ni = 1.41421356f * erfinv_xla(x1);
            // uniform(minval=1e-7, maxval=1): MUST be bit-exact (no contraction)
            const float ulo = 1e-7f;
            const float udf = 1.0f - 1e-7f;
            float fu = bits_to_f01(ru[b]);
            float u  = fmaxf(ulo, __fadd_rn(__fmul_rn(fu, udf), ulo));

            float ar = fmaf(nc, nr, br);
            float ai = fmaf(nc, ni, bi);
            float logit = logf(ar * ar + ai * ai + 1e-20f);
            float g = logf(-logf(u));
            float v = logit - g;
            if (v > best[b]) { best[b] = v; bidx[b] = s; }  // strict > keeps first max
        }
    }

    // reduce over threadIdx.y, then one atomic per (b,d) per block
    if (y == 1) {
#pragma unroll
        for (int b = 0; b < 4; b++) { red_v[b][d] = best[b]; red_i[b][d] = bidx[b]; }
    }
    __syncthreads();
    if (y == 0) {
#pragma unroll
        for (int b = 0; b < 4; b++) {
            float ov = red_v[b][d];
            uint32_t oi = red_i[b][d];
            if (ov > best[b] || (ov == best[b] && oi < bidx[b])) { best[b] = ov; bidx[b] = oi; }
            uint32_t mu = __float_as_uint(best[b]);
            mu = (mu & 0x80000000u) ? ~mu : (mu | 0x80000000u);  // order-preserving map
            unsigned long long kp =
                ((unsigned long long)mu << 32) |
                (unsigned long long)(0xFFFFFFFFu - bidx[b]);     // tie -> smaller s wins
            atomicMax(&keys[b * 128 + d], kp);
        }
    }
}

// ---------------- kernel 3: gather hits + bias mean ----------------
__global__ __launch_bounds__(128) void qsl_out(const unsigned long long* __restrict__ keys,
                                               const float* __restrict__ mW,
                                               const float* __restrict__ mb,
                                               float* __restrict__ out) {
    int b = blockIdx.x, e = threadIdx.x;
    __shared__ uint32_t idx_s[128];
    unsigned long long kp = keys[b * 128 + e];
    idx_s[e] = 0xFFFFFFFFu - (uint32_t)(kp & 0xFFFFFFFFull);
    __syncthreads();

    float acc = 0.f;
#pragma unroll
    for (int n = 0; n < 16; n++) acc += mb[n * 128 + e];
    for (int dd = 0; dd < 128; dd++) {
        uint32_t m = idx_s[dd];           // block-uniform -> no divergence
        if (m < 16u) acc += mW[(m * 128 + e) * 128 + dd];
    }
    out[b * 128 + e] = acc * 0.0625f;
}

// ---------------- launcher ----------------
extern "C" void kernel_launch(void* const* d_in, const int* in_sizes, int n_in,
                              void* d_out, int out_size, void* d_ws, size_t ws_size,
                              hipStream_t stream) {
    (void)in_sizes; (void)n_in; (void)out_size; (void)ws_size;
    const float* qre = (const float*)d_in[1];
    const float* qim = (const float*)d_in[2];
    const float* ang = (const float*)d_in[3];
    const float* ent = (const float*)d_in[4];
    const float* mW  = (const float*)d_in[5];
    const float* mb  = (const float*)d_in[6];
    float* out = (float*)d_out;

    float* ws_f = (float*)d_ws;                                        // ew[256] + phase[2]
    unsigned long long* keys = (unsigned long long*)((char*)d_ws + 4096); // 512 slots

    // jax.random.split(key(1), 3), partitionable/fold-in mode: kn[i] = enc((0,1),(0,i))
    uint32_t kn[6];
    tf2x32(0u, 1u, 0u, 0u, kn[0], kn[1]);
    tf2x32(0u, 1u, 0u, 1u, kn[2], kn[3]);
    tf2x32(0u, 1u, 0u, 2u, kn[4], kn[5]);

    float coh = expf(-0.01f);                              // exp(-1/DECO_T)
    float nc  = (0.70710678f * (1.0f - coh)) * 0.1f;       // inv_sqrt2*(1-coh)*0.1

    hipLaunchKernelGGL(qsl_prep, dim3(1), dim3(512), 0, stream, ang, ent, ws_f, keys);
    hipLaunchKernelGGL(qsl_main, dim3(2048), dim3(128, 2), 0, stream,
                       qre, qim, ws_f, keys,
                       kn[0], kn[1], kn[2], kn[3], kn[4], kn[5], coh, nc);
    hipLaunchKernelGGL(qsl_out, dim3(4), dim3(128), 0, stream, keys, mW, mb, out);
}

// Round 2
// 170.211 us; speedup vs baseline: 2.3980x; 2.3980x over previous
//
#include <hip/hip_runtime.h>
#include <stdint.h>
#include <math.h>

// ---------------- problem constants ----------------
constexpr int D_ = 128;                 // quantum_dim
constexpr int KDIM = 4096;              // S / NQ
constexpr uint32_t SD_ = 65536u * 128u; // S*D per-batch stride in flat [B,S,D]
constexpr uint32_t QSTR = 4096u * 128u; // n-stride per q

// noise magnitude bound: nc * max|normal| = 7.04e-4 * 5.2 -> pad to 4.5e-3
#define DELTA  0.0045f
#define MARGIN 0.002f

// ---------------- threefry2x32 (JAX-exact, 20 rounds) ----------------
__host__ __device__ static inline void tfround(uint32_t& x0, uint32_t& x1, int r) {
    x0 += x1;
    x1 = (x1 << r) | (x1 >> (32 - r));
    x1 ^= x0;
}

__host__ __device__ static inline void tf2x32(uint32_t k0, uint32_t k1,
                                              uint32_t x0, uint32_t x1,
                                              uint32_t& o0, uint32_t& o1) {
    uint32_t ks2 = k0 ^ k1 ^ 0x1BD11BDAu;
    x0 += k0; x1 += k1;
    tfround(x0, x1, 13); tfround(x0, x1, 15); tfround(x0, x1, 26); tfround(x0, x1, 6);
    x0 += k1;  x1 += ks2 + 1u;
    tfround(x0, x1, 17); tfround(x0, x1, 29); tfround(x0, x1, 16); tfround(x0, x1, 24);
    x0 += ks2; x1 += k0 + 2u;
    tfround(x0, x1, 13); tfround(x0, x1, 15); tfround(x0, x1, 26); tfround(x0, x1, 6);
    x0 += k0;  x1 += k1 + 3u;
    tfround(x0, x1, 17); tfround(x0, x1, 29); tfround(x0, x1, 16); tfround(x0, x1, 24);
    x0 += k1;  x1 += ks2 + 4u;
    tfround(x0, x1, 13); tfround(x0, x1, 15); tfround(x0, x1, 26); tfround(x0, x1, 6);
    x0 += ks2; x1 += k0 + 5u;
    o0 = x0; o1 = x1;
}

// bits -> [0,1): bitcast((bits>>9)|0x3f800000) - 1
__device__ __forceinline__ float bits_to_f01(uint32_t r) {
    return __uint_as_float((r >> 9) | 0x3f800000u) - 1.0f;
}

// XLA ErfInv32 (Giles polynomial) — exact path only
__device__ __forceinline__ float erfinv_xla(float x) {
    float w = -log1pf(-x * x);
    float p;
    if (w < 5.0f) {
        w -= 2.5f;
        p = 2.81022636e-08f;
        p = fmaf(p, w, 3.43273939e-07f);
        p = fmaf(p, w, -3.5233877e-06f);
        p = fmaf(p, w, -4.39150654e-06f);
        p = fmaf(p, w, 0.00021858087f);
        p = fmaf(p, w, -0.00125372503f);
        p = fmaf(p, w, -0.00417768164f);
        p = fmaf(p, w, 0.246640727f);
        p = fmaf(p, w, 1.50140941f);
    } else {
        w = sqrtf(w) - 3.0f;
        p = -0.000200214257f;
        p = fmaf(p, w, 0.000100950558f);
        p = fmaf(p, w, 0.00134934322f);
        p = fmaf(p, w, -0.00367342844f);
        p = fmaf(p, w, 0.00573950773f);
        p = fmaf(p, w, -0.0076224613f);
        p = fmaf(p, w, 0.00943887047f);
        p = fmaf(p, w, 1.00167406f);
        p = fmaf(p, w, 2.83297682f);
    }
    return p * x;
}

// ---------------- kernel 1: prep ----------------
__global__ __launch_bounds__(512) void qsl_prep(const float* __restrict__ ang,
                                                const float* __restrict__ ent,
                                                float* __restrict__ ws_f,
                                                unsigned long long* __restrict__ keys) {
    int t = threadIdx.x;
    keys[t] = 0ULL;
    if (t < 16) {
        float row[16];
        float m = -INFINITY;
        for (int j = 0; j < 16; j++) { row[j] = ent[t * 16 + j]; m = fmaxf(m, row[j]); }
        float s = 0.f;
        for (int j = 0; j < 16; j++) { row[j] = expf(row[j] - m); s += row[j]; }
        for (int j = 0; j < 16; j++) ws_f[t * 16 + j] = row[j] / s;
    }
    if (t == 0) {
        float a = 0.f;
        for (int i = 0; i < 48; i++) a += ang[i];
        ws_f[256] = cosf(a);
        ws_f[257] = sinf(a);
    }
}

// ---------------- kernel 2: main ----------------
__global__ __launch_bounds__(256) void qsl_main(const float* __restrict__ qre,
                                                const float* __restrict__ qim,
                                                const float* __restrict__ ws_f,
                                                unsigned long long* __restrict__ keys,
                                                uint32_t kA0, uint32_t kA1,
                                                uint32_t kB0, uint32_t kB1,
                                                uint32_t kC0, uint32_t kC1,
                                                float coh, float nc) {
    __shared__ float ew_s[256];
    __shared__ float red_v[4][128];
    __shared__ uint32_t red_i[4][128];

    const int d = threadIdx.x;               // 0..127
    const int y = threadIdx.y;               // 0..1
    const int kk = blockIdx.x * 2 + y;       // 0..4095

    ew_s[y * 128 + d] = ws_f[y * 128 + d];
    __syncthreads();
    const float pr = ws_f[256], pi = ws_f[257];

    // ---- load the 16 q-rows of this (k,d) column factor
    float are[16], aim[16];
#pragma unroll
    for (int p = 0; p < 16; p++) {
        int off = (p * KDIM + kk) * D_ + d;
        are[p] = qre[off];
        aim[p] = qim[off];
    }

    // ---- per-q deterministic logit bounds (b-independent)
    float lo_a[16], hi_a[16];
#pragma unroll
    for (int q = 0; q < 16; q++) {
        float mr = 0.f, mi = 0.f;
#pragma unroll
        for (int p = 0; p < 16; p++) {
            float w = ew_s[q * 16 + p];
            mr = fmaf(w, are[p], mr);
            mi = fmaf(w, aim[p], mi);
        }
        mr = fmaf(0.8f, mr, 0.2f * are[q]);
        mi = fmaf(0.8f, mi, 0.2f * aim[q]);
        float sr = mr * pr - mi * pi;
        float si = mr * pi + mi * pr;
        float br = sr * coh, bi = si * coh;
        float abr = fabsf(br), abi = fabsf(bi);
        float hr = abr + DELTA, hq = abi + DELTA;
        hi_a[q] = __logf(fmaf(hr, hr, hq * hq) + 1e-20f);
        float lr = fmaxf(abr - DELTA, 0.f), lq = fmaxf(abi - DELTA, 0.f);
        lo_a[q] = __logf(fmaf(lr, lr, lq * lq) + 1e-20f);
    }

    float best[4];
    uint32_t bidx[4];

    for (int b = 0; b < 4; b++) {
        const uint32_t nbase = (uint32_t)kk * 128u + (uint32_t)d + (uint32_t)b * SD_;

        // ---- pass 1: u-threefry + fast Gumbel, running lower-bound max
        float g_a[16];
        float M = -INFINITY;
#pragma unroll
        for (int q = 0; q < 16; q++) {
            uint32_t w0, w1;
            tf2x32(kC0, kC1, 0u, nbase + (uint32_t)q * QSTR, w0, w1);
            float fu = bits_to_f01(w0 ^ w1);
            const float ulo = 1e-7f;
            const float udf = 1.0f - 1e-7f;
            float u = fmaxf(ulo, __fadd_rn(__fmul_rn(fu, udf), ulo));
            // fast -ln(u): series near u->1 (avoids v_log cancellation), v_log otherwise
            float nz = 1.0f - u;                                   // exact for u>=0.5
            float t_ser = nz * fmaf(nz, fmaf(nz, 0.33333334f, 0.5f), 1.0f);
            float t = (u > 0.999f) ? t_ser : -__logf(u);
            float g = __logf(t);
            g_a[q] = g;
            M = fmaxf(M, lo_a[q] - g);
        }

        // ---- candidate mask: could this sample beat the best lower bound?
        uint32_t mask = 0u;
#pragma unroll
        for (int q = 0; q < 16; q++)
            if (hi_a[q] - g_a[q] >= M - MARGIN) mask |= (1u << q);

        // ---- exact (JAX-bit-identical) evaluation, compacted per lane
        float bv = -INFINITY;
        uint32_t bs = 0u;
        while (__any((int)(mask != 0u))) {
            if (mask) {
                int q = __ffs(mask) - 1;
                mask &= mask - 1u;
                // recompute mix exactly as the validated round-1 sequence
                float mr = 0.f, mi = 0.f;
#pragma unroll
                for (int p = 0; p < 16; p++) {
                    float w = ew_s[q * 16 + p];
                    mr = fmaf(w, are[p], mr);
                    mi = fmaf(w, aim[p], mi);
                }
                float aqr = are[0], aqi = aim[0];
#pragma unroll
                for (int p = 1; p < 16; p++) {
                    aqr = (q == p) ? are[p] : aqr;
                    aqi = (q == p) ? aim[p] : aqi;
                }
                mr = fmaf(0.8f, mr, 0.2f * aqr);
                mi = fmaf(0.8f, mi, 0.2f * aqi);
                float sr = mr * pr - mi * pi;
                float si = mr * pi + mi * pr;
                float br = sr * coh, bi = si * coh;

                uint32_t n = nbase + (uint32_t)q * QSTR;
                uint32_t w0, w1, rn0, rn1, ru;
                tf2x32(kA0, kA1, 0u, n, w0, w1); rn0 = w0 ^ w1;
                tf2x32(kB0, kB1, 0u, n, w0, w1); rn1 = w0 ^ w1;
                tf2x32(kC0, kC1, 0u, n, w0, w1); ru  = w0 ^ w1;

                const float nlo = -0.99999994f;
                const float ndf = 1.0f - nlo;
                float f0 = bits_to_f01(rn0);
                float x0 = fmaxf(nlo, __fadd_rn(__fmul_rn(f0, ndf), nlo));
                float f1 = bits_to_f01(rn1);
                float x1 = fmaxf(nlo, __fadd_rn(__fmul_rn(f1, ndf), nlo));
                float nr = 1.41421356f * erfinv_xla(x0);
                float ni = 1.41421356f * erfinv_xla(x1);
                const float ulo = 1e-7f;
                const float udf = 1.0f - 1e-7f;
                float fu = bits_to_f01(ru);
                float u  = fmaxf(ulo, __fadd_rn(__fmul_rn(fu, udf), ulo));

                float ar = fmaf(nc, nr, br);
                float ai = fmaf(nc, ni, bi);
                float logit = logf(ar * ar + ai * ai + 1e-20f);
                float gx = logf(-logf(u));
                float v = logit - gx;
                uint32_t s = (uint32_t)q * (uint32_t)KDIM + (uint32_t)kk;
                if (v > bv) { bv = v; bs = s; }  // q ascending -> first-max kept
            }
        }
        best[b] = bv;
        bidx[b] = bs;
    }

    // ---- reduce over threadIdx.y, then one atomic per (b,d) per block
    if (y == 1) {
#pragma unroll
        for (int b = 0; b < 4; b++) { red_v[b][d] = best[b]; red_i[b][d] = bidx[b]; }
    }
    __syncthreads();
    if (y == 0) {
#pragma unroll
        for (int b = 0; b < 4; b++) {
            float ov = red_v[b][d];
            uint32_t oi = red_i[b][d];
            if (ov > best[b] || (ov == best[b] && oi < bidx[b])) { best[b] = ov; bidx[b] = oi; }
            uint32_t mu = __float_as_uint(best[b]);
            mu = (mu & 0x80000000u) ? ~mu : (mu | 0x80000000u);
            unsigned long long kp =
                ((unsigned long long)mu << 32) |
                (unsigned long long)(0xFFFFFFFFu - bidx[b]);
            atomicMax(&keys[b * 128 + d], kp);
        }
    }
}

// ---------------- kernel 3: gather hits + bias mean ----------------
__global__ __launch_bounds__(128) void qsl_out(const unsigned long long* __restrict__ keys,
                                               const float* __restrict__ mW,
                                               const float* __restrict__ mb,
                                               float* __restrict__ out) {
    int b = blockIdx.x, e = threadIdx.x;
    __shared__ uint32_t idx_s[128];
    unsigned long long kp = keys[b * 128 + e];
    idx_s[e] = 0xFFFFFFFFu - (uint32_t)(kp & 0xFFFFFFFFull);
    __syncthreads();

    float acc = 0.f;
#pragma unroll
    for (int n = 0; n < 16; n++) acc += mb[n * 128 + e];
    for (int dd = 0; dd < 128; dd++) {
        uint32_t m = idx_s[dd];
        if (m < 16u) acc += mW[(m * 128 + e) * 128 + dd];
    }
    out[b * 128 + e] = acc * 0.0625f;
}

// ---------------- launcher ----------------
extern "C" void kernel_launch(void* const* d_in, const int* in_sizes, int n_in,
                              void* d_out, int out_size, void* d_ws, size_t ws_size,
                              hipStream_t stream) {
    (void)in_sizes; (void)n_in; (void)out_size; (void)ws_size;
    const float* qre = (const float*)d_in[1];
    const float* qim = (const float*)d_in[2];
    const float* ang = (const float*)d_in[3];
    const float* ent = (const float*)d_in[4];
    const float* mW  = (const float*)d_in[5];
    const float* mb  = (const float*)d_in[6];
    float* out = (float*)d_out;

    float* ws_f = (float*)d_ws;
    unsigned long long* keys = (unsigned long long*)((char*)d_ws + 4096);

    uint32_t kn[6];
    tf2x32(0u, 1u, 0u, 0u, kn[0], kn[1]);
    tf2x32(0u, 1u, 0u, 1u, kn[2], kn[3]);
    tf2x32(0u, 1u, 0u, 2u, kn[4], kn[5]);

    float coh = expf(-0.01f);
    float nc  = (0.70710678f * (1.0f - coh)) * 0.1f;

    hipLaunchKernelGGL(qsl_prep, dim3(1), dim3(512), 0, stream, ang, ent, ws_f, keys);
    hipLaunchKernelGGL(qsl_main, dim3(2048), dim3(128, 2), 0, stream,
                       qre, qim, ws_f, keys,
                       kn[0], kn[1], kn[2], kn[3], kn[4], kn[5], coh, nc);
    hipLaunchKernelGGL(qsl_out, dim3(4), dim3(128), 0, stream, keys, mW, mb, out);
}